// Round 3
// baseline (602.497 us; speedup 1.0000x reference)
//
#include <hip/hip_runtime.h>
#include <math.h>

#define N_    512
#define L_    64
#define DH    256
#define DX    64
#define Q_    8192
#define NTYP  16
#define NMEM  262144
#define NSEG  32768

// ---------------------------------------------------------------- init
__global__ void k_init(int* __restrict__ em, int* __restrict__ eqcnt) {
    int t = blockIdx.x * blockDim.x + threadIdx.x;
    if (t < N_) em[t] = 0x7fffffff;   // segment_min identity (int32 max)
    if (t == 0) *eqcnt = 0;
}

// ---------------------------------------------------- segment scatter-sum
// x_sum[grp[e]][d] += tok_emb[mem[e]][d]; one wave = one edge (64 dims)
__global__ __launch_bounds__(256) void k_scatter(const float* __restrict__ tok,
                                                 const int* __restrict__ mem,
                                                 const int* __restrict__ grp,
                                                 float* __restrict__ xsum) {
    long tid = (long)blockIdx.x * 256 + threadIdx.x;
    int e = (int)(tid >> 6);
    int d = (int)(tid & 63);
    int m = mem[e];
    int g = grp[e];
    atomicAdd(&xsum[(size_t)g * 64 + d], tok[(size_t)m * 64 + d]);
}

// ------------------- qk = (cat(h[idx,src],h[idx,dst]) @ Wq^T + bq) @ Wk ; bterm = bk.qp
// 16 queries per block, 256 threads
__global__ __launch_bounds__(256) void k_qpk(const float* __restrict__ h,
                                             const float* __restrict__ Wq,
                                             const float* __restrict__ bq,
                                             const float* __restrict__ Wk,
                                             const float* __restrict__ bk,
                                             const int* __restrict__ idx,
                                             const int* __restrict__ src,
                                             const int* __restrict__ dst,
                                             float* __restrict__ qk,
                                             float* __restrict__ bterm) {
    __shared__ float qs[16 * 512];    // 32 KB: q_in staging
    __shared__ float qps[16 * 256];   // 16 KB: qp staging
    int qb = blockIdx.x * 16;
    for (int i = threadIdx.x; i < 2048; i += 256) {   // 2048 float4 = 16 q * 128
        int qq = i >> 7;
        int j4 = i & 127;
        int gq = qb + qq;
        int r = idx[gq];
        int pos = (j4 < 64) ? src[gq] : dst[gq];
        int off = (j4 & 63) * 4;
        float4 v = *(const float4*)(h + ((size_t)r * 64 + pos) * 256 + off);
        *(float4*)(qs + qq * 512 + j4 * 4) = v;
    }
    __syncthreads();

    // qp[qb+q][d] for d = threadIdx.x
    int d = threadIdx.x;
    float acc[16];
#pragma unroll
    for (int r = 0; r < 16; r++) acc[r] = 0.f;
    {
        const float* w = Wq + (size_t)d * 512;
        for (int j = 0; j < 512; j += 4) {
            float4 wv = *(const float4*)(w + j);
#pragma unroll
            for (int r = 0; r < 16; r++) {
                float4 hv = *(const float4*)(qs + r * 512 + j);   // b128 broadcast
                acc[r] = fmaf(wv.x, hv.x, fmaf(wv.y, hv.y,
                         fmaf(wv.z, hv.z, fmaf(wv.w, hv.w, acc[r]))));
            }
        }
    }
    float b = bq[d];
#pragma unroll
    for (int r = 0; r < 16; r++) qps[r * 256 + d] = acc[r] + b;
    __syncthreads();

    // bterm[q] = bk . qp[q]
    if (threadIdx.x < 16) {
        float s = 0.f;
        const float* qpr = qps + threadIdx.x * 256;
        for (int j = 0; j < 256; j++) s = fmaf(bk[j], qpr[j], s);
        bterm[qb + threadIdx.x] = s;
    }

    // qk[qb+q][e] = sum_d qp[q][d] * Wk[d][e], e = threadIdx.x
    int e = threadIdx.x;
    float qkacc[16];
#pragma unroll
    for (int r = 0; r < 16; r++) qkacc[r] = 0.f;
    for (int j = 0; j < 256; j += 4) {
        float w0 = Wk[(size_t)(j + 0) * 256 + e];   // coalesced across e
        float w1 = Wk[(size_t)(j + 1) * 256 + e];
        float w2 = Wk[(size_t)(j + 2) * 256 + e];
        float w3 = Wk[(size_t)(j + 3) * 256 + e];
#pragma unroll
        for (int r = 0; r < 16; r++) {
            float4 qv = *(const float4*)(qps + r * 256 + j);   // b128 broadcast
            qkacc[r] = fmaf(qv.x, w0, fmaf(qv.y, w1,
                       fmaf(qv.z, w2, fmaf(qv.w, w3, qkacc[r]))));
        }
    }
#pragma unroll
    for (int r = 0; r < 16; r++) qk[(size_t)(qb + r) * 256 + e] = qkacc[r];
}

// ------------------------------------ attention: one block per h-row (idx sorted)
// s[q,l] = (h[row,l].qk[q] + bterm[q]) / 16 ; softmax over valid l ; attn = a @ x_grp[row]
__global__ __launch_bounds__(256) void k_attn2(const float* __restrict__ h,
                                               const float* __restrict__ qk,
                                               const float* __restrict__ bterm,
                                               const float* __restrict__ xsum,
                                               const int* __restrict__ pos2grp,
                                               const int* __restrict__ msk,
                                               const int* __restrict__ idx,
                                               float* __restrict__ attn) {
    __shared__ float hs[64 * 256];   // 64 KB
    __shared__ float xg[64 * 64];    // 16 KB
    __shared__ int   gl[64];
    __shared__ int   vm[64];
    __shared__ float qs[256];
    __shared__ float sl[64];
    __shared__ float al[64];
    __shared__ float part[4][64];

    int row = blockIdx.x;
    // binary search query range [qlo,qhi) with idx[.] == row (idx sorted)
    int lo = 0, hi = Q_;
    while (lo < hi) { int mid = (lo + hi) >> 1; if (idx[mid] < row) lo = mid + 1; else hi = mid; }
    int qlo = lo;
    hi = Q_;
    while (lo < hi) { int mid = (lo + hi) >> 1; if (idx[mid] <= row) lo = mid + 1; else hi = mid; }
    int qhi = lo;
    if (qlo == qhi) return;

    int t = threadIdx.x;
    if (t < 64) {
        gl[t] = pos2grp[row * 64 + t];
        vm[t] = msk[row * 64 + t];
    }
    __syncthreads();
    {
        const float4* hsrc = (const float4*)(h + (size_t)row * 64 * 256);
        float4* hdst = (float4*)hs;
        for (int i = t; i < 4096; i += 256) hdst[i] = hsrc[i];
        for (int i = t; i < 1024; i += 256) {        // 64 l * 16 float4
            int l = i >> 4, c = i & 15;
            *(float4*)(xg + l * 64 + c * 4) = *(const float4*)(xsum + (size_t)gl[l] * 64 + c * 4);
        }
    }
    __syncthreads();

    int wave = t >> 6, lane = t & 63;
    for (int q = qlo; q < qhi; q++) {
        qs[t] = qk[(size_t)q * 256 + t];
        float bt = bterm[q];
        __syncthreads();

        // s[l] for l = wave*16+i
        for (int i = 0; i < 16; i++) {
            int l = wave * 16 + i;
            const float* kr = hs + l * 256;
            float p = 0.f;
#pragma unroll
            for (int k = 0; k < 4; k++) p += kr[lane + 64 * k] * qs[lane + 64 * k];
#pragma unroll
            for (int off = 32; off; off >>= 1) p += __shfl_xor(p, off);
            if (lane == 0) sl[l] = vm[l] ? (p + bt) * 0.0625f : -INFINITY;
        }
        __syncthreads();

        if (wave == 0) {
            float s = sl[lane];
            float m = s;
#pragma unroll
            for (int off = 32; off; off >>= 1) m = fmaxf(m, __shfl_xor(m, off));
            float ev = expf(s - m);
            float sum = ev;
#pragma unroll
            for (int off = 32; off; off >>= 1) sum += __shfl_xor(sum, off);
            al[lane] = ev / sum;
        }
        __syncthreads();

        int dd = lane;
        float a = 0.f;
        for (int i = 0; i < 16; i++) {
            int l = wave * 16 + i;
            a = fmaf(al[l], xg[l * 64 + dd], a);
        }
        part[wave][dd] = a;
        __syncthreads();
        if (wave == 0) {
            attn[(size_t)q * 64 + dd] = part[0][dd] + part[1][dd] + part[2][dd] + part[3][dd];
        }
    }
}

// --------------------------- logit = cat(q_in, attn) @ Wrel^T + brel ; metrics
// 16 queries per block, 256 threads: thread = (q, typ)
#define VSTRIDE 580   // 576 rounded to x4 for float4 LDS reads; 580%32=4 -> no conflict
__global__ __launch_bounds__(256) void k_logit(const float* __restrict__ h,
                                               const float* __restrict__ Wrel,
                                               const float* __restrict__ brel,
                                               const int* __restrict__ idx,
                                               const int* __restrict__ src,
                                               const int* __restrict__ dst,
                                               const float* __restrict__ attn,
                                               const int* __restrict__ typ,
                                               float* __restrict__ out,
                                               int* __restrict__ em,
                                               int* __restrict__ eqcnt) {
    __shared__ float vs[16 * VSTRIDE];
    __shared__ int cnt;
    int qb = blockIdx.x * 16;
    if (threadIdx.x == 0) cnt = 0;
    for (int i = threadIdx.x; i < 16 * 576; i += 256) {
        int qq = i / 576, j = i - qq * 576;
        int gq = qb + qq;
        float v;
        if (j < 512) {
            int r = idx[gq];
            int pos = (j < 256) ? src[gq] : dst[gq];
            v = h[((size_t)r * 64 + pos) * 256 + (j & 255)];
        } else {
            v = attn[(size_t)gq * 64 + (j - 512)];
        }
        vs[qq * VSTRIDE + j] = v;
    }
    __syncthreads();

    int qq = threadIdx.x >> 4, tt = threadIdx.x & 15;
    const float* wr = Wrel + (size_t)tt * 576;     // 36 KB, L1/L2 resident
    const float* vv = vs + qq * VSTRIDE;
    float acc = 0.f;
    for (int j = 0; j < 576; j += 4) {
        float4 wv = *(const float4*)(wr + j);
        float4 xv = *(const float4*)(vv + j);
        acc = fmaf(wv.x, xv.x, fmaf(wv.y, xv.y,
              fmaf(wv.z, xv.z, fmaf(wv.w, xv.w, acc))));
    }
    acc += brel[tt];
    int gq = qb + qq;
    out[(size_t)gq * 16 + tt] = acc;

    int eq = ((acc > 0.f) == (typ[gq * 16 + tt] > 0)) ? 1 : 0;
    unsigned long long mask = __ballot(eq);
    int lane = threadIdx.x & 63;
    if ((lane & 15) == 0) {
        unsigned bits = (unsigned)((mask >> (lane & 48)) & 0xFFFFull);
        atomicAdd(&cnt, __popc(bits));
        int all = (bits == 0xFFFFu) ? 1 : 0;
        atomicMin(&em[idx[gq]], all);
    }
    __syncthreads();
    if (threadIdx.x == 0) atomicAdd(eqcnt, cnt);
}

// ---------------------------------------------------------------- finalize
__global__ void k_fin(const int* __restrict__ em, const int* __restrict__ eqcnt,
                      float* __restrict__ out) {
    __shared__ float ssum[512];
    int t = threadIdx.x;
    int v = em[t];
    out[131074 + t] = (float)v;
    ssum[t] = (float)v;
    __syncthreads();
    for (int s = 256; s; s >>= 1) {
        if (t < s) ssum[t] += ssum[t + s];
        __syncthreads();
    }
    if (t == 0) {
        out[131073] = ssum[0] / 512.0f;
        out[131072] = (float)(*eqcnt) / (float)(Q_ * NTYP);
    }
}

extern "C" void kernel_launch(void* const* d_in, const int* in_sizes, int n_in,
                              void* d_out, int out_size, void* d_ws, size_t ws_size,
                              hipStream_t stream) {
    const float* h    = (const float*)d_in[0];
    const float* tok  = (const float*)d_in[1];
    const float* Wq   = (const float*)d_in[2];
    const float* bq   = (const float*)d_in[3];
    const float* Wk   = (const float*)d_in[4];
    const float* bk   = (const float*)d_in[5];
    const float* Wrel = (const float*)d_in[6];
    const float* brel = (const float*)d_in[7];
    const int* mem     = (const int*)d_in[8];
    const int* grp     = (const int*)d_in[9];
    const int* pos2grp = (const int*)d_in[10];
    const int* msk     = (const int*)d_in[11];
    const int* idx     = (const int*)d_in[12];
    const int* src     = (const int*)d_in[13];
    const int* dst     = (const int*)d_in[14];
    const int* typ     = (const int*)d_in[15];
    float* out = (float*)d_out;

    char* ws = (char*)d_ws;
    float* xsum  = (float*)ws;                          // 8 MB
    float* qk    = (float*)(ws + (size_t)( 8 << 20));   // 8 MB
    float* bterm = (float*)(ws + (size_t)(16 << 20));   // 32 KB
    float* attn  = (float*)(ws + (size_t)(17 << 20));   // 2 MB
    int* em      = (int*)  (ws + (size_t)(19 << 20));   // 2 KB
    int* eqcnt   = (int*)  (ws + (size_t)(19 << 20) + 4096);

    hipMemsetAsync(xsum, 0, (size_t)NSEG * 64 * 4, stream);
    k_init<<<1, 512, 0, stream>>>(em, eqcnt);
    k_scatter<<<NMEM * 64 / 256, 256, 0, stream>>>(tok, mem, grp, xsum);
    k_qpk<<<Q_ / 16, 256, 0, stream>>>(h, Wq, bq, Wk, bk, idx, src, dst, qk, bterm);
    k_attn2<<<N_, 256, 0, stream>>>(h, qk, bterm, xsum, pos2grp, msk, idx, attn);
    k_logit<<<Q_ / 16, 256, 0, stream>>>(h, Wrel, brel, idx, src, dst, attn, typ, out, em, eqcnt);
    k_fin<<<1, 512, 0, stream>>>(em, eqcnt, out);
}

// Round 4
// 399.053 us; speedup vs baseline: 1.5098x; 1.5098x over previous
//
#include <hip/hip_runtime.h>
#include <math.h>

#define N_    512
#define L_    64
#define DH    256
#define DX    64
#define Q_    8192
#define NTYP  16
#define NMEM  262144
#define NSEG  32768

// ---------------------------------------------------------------- init
__global__ void k_init(int* __restrict__ em, int* __restrict__ eqcnt) {
    int t = blockIdx.x * blockDim.x + threadIdx.x;
    if (t < N_) em[t] = 0x7fffffff;   // segment_min identity (int32 max)
    if (t == 0) *eqcnt = 0;
}

// ---------------------------------------------------- segment scatter-sum
// x_sum[grp[e]][d] += tok_emb[mem[e]][d]; one wave = one edge (64 dims)
__global__ __launch_bounds__(256) void k_scatter(const float* __restrict__ tok,
                                                 const int* __restrict__ mem,
                                                 const int* __restrict__ grp,
                                                 float* __restrict__ xsum) {
    long tid = (long)blockIdx.x * 256 + threadIdx.x;
    int e = (int)(tid >> 6);
    int d = (int)(tid & 63);
    int m = mem[e];
    int g = grp[e];
    atomicAdd(&xsum[(size_t)g * 64 + d], tok[(size_t)m * 64 + d]);
}

// ------------------- qk = (cat(h[idx,src],h[idx,dst]) @ Wq^T + bq) @ Wk ; bterm = bk.qp
// 16 queries per block, 256 threads
__global__ __launch_bounds__(256) void k_qpk(const float* __restrict__ h,
                                             const float* __restrict__ Wq,
                                             const float* __restrict__ bq,
                                             const float* __restrict__ Wk,
                                             const float* __restrict__ bk,
                                             const int* __restrict__ idx,
                                             const int* __restrict__ src,
                                             const int* __restrict__ dst,
                                             float* __restrict__ qk,
                                             float* __restrict__ bterm) {
    __shared__ float qs[16 * 512];    // 32 KB: q_in staging
    __shared__ float qps[16 * 256];   // 16 KB: qp staging
    int qb = blockIdx.x * 16;
    for (int i = threadIdx.x; i < 2048; i += 256) {   // 2048 float4 = 16 q * 128
        int qq = i >> 7;
        int j4 = i & 127;
        int gq = qb + qq;
        int r = idx[gq];
        int pos = (j4 < 64) ? src[gq] : dst[gq];
        int off = (j4 & 63) * 4;
        float4 v = *(const float4*)(h + ((size_t)r * 64 + pos) * 256 + off);
        *(float4*)(qs + qq * 512 + j4 * 4) = v;
    }
    __syncthreads();

    // qp[qb+q][d] for d = threadIdx.x
    int d = threadIdx.x;
    float acc[16];
#pragma unroll
    for (int r = 0; r < 16; r++) acc[r] = 0.f;
    {
        const float* w = Wq + (size_t)d * 512;
        for (int j = 0; j < 512; j += 4) {
            float4 wv = *(const float4*)(w + j);
#pragma unroll
            for (int r = 0; r < 16; r++) {
                float4 hv = *(const float4*)(qs + r * 512 + j);   // b128 broadcast
                acc[r] = fmaf(wv.x, hv.x, fmaf(wv.y, hv.y,
                         fmaf(wv.z, hv.z, fmaf(wv.w, hv.w, acc[r]))));
            }
        }
    }
    float b = bq[d];
#pragma unroll
    for (int r = 0; r < 16; r++) qps[r * 256 + d] = acc[r] + b;
    __syncthreads();

    // bterm[q] = bk . qp[q]
    if (threadIdx.x < 16) {
        float s = 0.f;
        const float* qpr = qps + threadIdx.x * 256;
        for (int j = 0; j < 256; j++) s = fmaf(bk[j], qpr[j], s);
        bterm[qb + threadIdx.x] = s;
    }

    // qk[qb+q][e] = sum_d qp[q][d] * Wk[d][e], e = threadIdx.x
    int e = threadIdx.x;
    float qkacc[16];
#pragma unroll
    for (int r = 0; r < 16; r++) qkacc[r] = 0.f;
    for (int j = 0; j < 256; j += 4) {
        float w0 = Wk[(size_t)(j + 0) * 256 + e];   // coalesced across e
        float w1 = Wk[(size_t)(j + 1) * 256 + e];
        float w2 = Wk[(size_t)(j + 2) * 256 + e];
        float w3 = Wk[(size_t)(j + 3) * 256 + e];
#pragma unroll
        for (int r = 0; r < 16; r++) {
            float4 qv = *(const float4*)(qps + r * 256 + j);   // b128 broadcast
            qkacc[r] = fmaf(qv.x, w0, fmaf(qv.y, w1,
                       fmaf(qv.z, w2, fmaf(qv.w, w3, qkacc[r]))));
        }
    }
#pragma unroll
    for (int r = 0; r < 16; r++) qk[(size_t)(qb + r) * 256 + e] = qkacc[r];
}

// ------------------------------------ attention: one WAVE per query, no LDS
// s[l] = (h[row,l,:].qk[q,:] + bterm[q]) / 16 ; softmax over valid l ;
// attn[q,d] = sum_l a[l] * xsum[pos2grp[row,l], d]
__global__ __launch_bounds__(256) void k_attn3(const float* __restrict__ h,
                                               const float* __restrict__ qk,
                                               const float* __restrict__ bterm,
                                               const float* __restrict__ xsum,
                                               const int* __restrict__ pos2grp,
                                               const int* __restrict__ msk,
                                               const int* __restrict__ idx,
                                               float* __restrict__ attn) {
    int wid  = threadIdx.x >> 6;
    int lane = threadIdx.x & 63;
    int q = blockIdx.x * 4 + wid;          // grid = Q/4, always in range
    int row = idx[q];                       // wave-uniform -> scalar

    // phase A: lane = l position; 256-dim dot h[row,lane,:] . qk[q,:]
    const float* hr  = h  + ((size_t)row * 64 + lane) * 256;
    const float* qkq = qk + (size_t)q * 256;   // wave-uniform -> scalar loads
    float p = 0.f;
#pragma unroll 4
    for (int j = 0; j < 256; j += 4) {
        float4 hv = *(const float4*)(hr + j);
        float4 qv = *(const float4*)(qkq + j);
        p = fmaf(hv.x, qv.x, fmaf(hv.y, qv.y,
            fmaf(hv.z, qv.z, fmaf(hv.w, qv.w, p))));
    }
    int v = msk[row * 64 + lane];
    float s = v ? (p + bterm[q]) * 0.0625f : -INFINITY;

    // wave softmax (>=1 valid lane guaranteed: msk[:,0]=1)
    float m = s;
#pragma unroll
    for (int off = 32; off; off >>= 1) m = fmaxf(m, __shfl_xor(m, off));
    float e = expf(s - m);
    float sum = e;
#pragma unroll
    for (int off = 32; off; off >>= 1) sum += __shfl_xor(sum, off);
    float a = e / sum;                     // a[lane] = weight of position lane

    // phase B: lane = output dim d; attn[q,d] = sum_l a[l]*xsum[g[l]*64+d]
    const int* p2g = pos2grp + row * 64;   // wave-uniform base -> scalar loads
    float acc = 0.f;
#pragma unroll 8
    for (int l = 0; l < 64; l++) {
        float al = __shfl(a, l);
        int g = p2g[l];                    // uniform per iteration
        acc = fmaf(al, xsum[(size_t)g * 64 + lane], acc);   // coalesced 256B
    }
    attn[(size_t)q * 64 + lane] = acc;
}

// --------------------------- logit = cat(q_in, attn) @ Wrel^T + brel ; metrics
// 16 queries per block, 256 threads: thread = (q, typ)
#define VSTRIDE 580   // 576 rounded to x4 for float4 LDS reads; 580%32=4 -> no conflict
__global__ __launch_bounds__(256) void k_logit(const float* __restrict__ h,
                                               const float* __restrict__ Wrel,
                                               const float* __restrict__ brel,
                                               const int* __restrict__ idx,
                                               const int* __restrict__ src,
                                               const int* __restrict__ dst,
                                               const float* __restrict__ attn,
                                               const int* __restrict__ typ,
                                               float* __restrict__ out,
                                               int* __restrict__ em,
                                               int* __restrict__ eqcnt) {
    __shared__ float vs[16 * VSTRIDE];
    __shared__ int cnt;
    int qb = blockIdx.x * 16;
    if (threadIdx.x == 0) cnt = 0;
    for (int i = threadIdx.x; i < 16 * 576; i += 256) {
        int qq = i / 576, j = i - qq * 576;
        int gq = qb + qq;
        float v;
        if (j < 512) {
            int r = idx[gq];
            int pos = (j < 256) ? src[gq] : dst[gq];
            v = h[((size_t)r * 64 + pos) * 256 + (j & 255)];
        } else {
            v = attn[(size_t)gq * 64 + (j - 512)];
        }
        vs[qq * VSTRIDE + j] = v;
    }
    __syncthreads();

    int qq = threadIdx.x >> 4, tt = threadIdx.x & 15;
    const float* wr = Wrel + (size_t)tt * 576;     // 36 KB, L1/L2 resident
    const float* vv = vs + qq * VSTRIDE;
    float acc = 0.f;
    for (int j = 0; j < 576; j += 4) {
        float4 wv = *(const float4*)(wr + j);
        float4 xv = *(const float4*)(vv + j);
        acc = fmaf(wv.x, xv.x, fmaf(wv.y, xv.y,
              fmaf(wv.z, xv.z, fmaf(wv.w, xv.w, acc))));
    }
    acc += brel[tt];
    int gq = qb + qq;
    out[(size_t)gq * 16 + tt] = acc;

    int eq = ((acc > 0.f) == (typ[gq * 16 + tt] > 0)) ? 1 : 0;
    unsigned long long mask = __ballot(eq);
    int lane = threadIdx.x & 63;
    if ((lane & 15) == 0) {
        unsigned bits = (unsigned)((mask >> (lane & 48)) & 0xFFFFull);
        atomicAdd(&cnt, __popc(bits));
        int all = (bits == 0xFFFFu) ? 1 : 0;
        atomicMin(&em[idx[gq]], all);
    }
    __syncthreads();
    if (threadIdx.x == 0) atomicAdd(eqcnt, cnt);
}

// ---------------------------------------------------------------- finalize
__global__ void k_fin(const int* __restrict__ em, const int* __restrict__ eqcnt,
                      float* __restrict__ out) {
    __shared__ float ssum[512];
    int t = threadIdx.x;
    int v = em[t];
    out[131074 + t] = (float)v;
    ssum[t] = (float)v;
    __syncthreads();
    for (int s = 256; s; s >>= 1) {
        if (t < s) ssum[t] += ssum[t + s];
        __syncthreads();
    }
    if (t == 0) {
        out[131073] = ssum[0] / 512.0f;
        out[131072] = (float)(*eqcnt) / (float)(Q_ * NTYP);
    }
}

extern "C" void kernel_launch(void* const* d_in, const int* in_sizes, int n_in,
                              void* d_out, int out_size, void* d_ws, size_t ws_size,
                              hipStream_t stream) {
    const float* h    = (const float*)d_in[0];
    const float* tok  = (const float*)d_in[1];
    const float* Wq   = (const float*)d_in[2];
    const float* bq   = (const float*)d_in[3];
    const float* Wk   = (const float*)d_in[4];
    const float* bk   = (const float*)d_in[5];
    const float* Wrel = (const float*)d_in[6];
    const float* brel = (const float*)d_in[7];
    const int* mem     = (const int*)d_in[8];
    const int* grp     = (const int*)d_in[9];
    const int* pos2grp = (const int*)d_in[10];
    const int* msk     = (const int*)d_in[11];
    const int* idx     = (const int*)d_in[12];
    const int* src     = (const int*)d_in[13];
    const int* dst     = (const int*)d_in[14];
    const int* typ     = (const int*)d_in[15];
    float* out = (float*)d_out;

    char* ws = (char*)d_ws;
    float* xsum  = (float*)ws;                          // 8 MB
    float* qk    = (float*)(ws + (size_t)( 8 << 20));   // 8 MB
    float* bterm = (float*)(ws + (size_t)(16 << 20));   // 32 KB
    float* attn  = (float*)(ws + (size_t)(17 << 20));   // 2 MB
    int* em      = (int*)  (ws + (size_t)(19 << 20));   // 2 KB
    int* eqcnt   = (int*)  (ws + (size_t)(19 << 20) + 4096);

    hipMemsetAsync(xsum, 0, (size_t)NSEG * 64 * 4, stream);
    k_init<<<1, 512, 0, stream>>>(em, eqcnt);
    k_scatter<<<NMEM * 64 / 256, 256, 0, stream>>>(tok, mem, grp, xsum);
    k_qpk<<<Q_ / 16, 256, 0, stream>>>(h, Wq, bq, Wk, bk, idx, src, dst, qk, bterm);
    k_attn3<<<Q_ / 4, 256, 0, stream>>>(h, qk, bterm, xsum, pos2grp, msk, idx, attn);
    k_logit<<<Q_ / 16, 256, 0, stream>>>(h, Wrel, brel, idx, src, dst, attn, typ, out, em, eqcnt);
    k_fin<<<1, 512, 0, stream>>>(em, eqcnt, out);
}

// Round 5
// 375.851 us; speedup vs baseline: 1.6030x; 1.0617x over previous
//
#include <hip/hip_runtime.h>
#include <math.h>

#define N_    512
#define L_    64
#define DH    256
#define DX    64
#define Q_    8192
#define NTYP  16
#define NMEM  262144
#define NSEG  32768

// ---------------------------------------------------------------- init
__global__ void k_init(int* __restrict__ em, int* __restrict__ eqcnt) {
    int t = blockIdx.x * blockDim.x + threadIdx.x;
    if (t < N_) em[t] = 0x7fffffff;   // segment_min identity (int32 max)
    if (t == 0) *eqcnt = 0;
}

// ---------------------------------------------------- segment scatter-sum
// x_sum[grp[e]][d] += tok_emb[mem[e]][d]; one wave = one edge (64 dims)
__global__ __launch_bounds__(256) void k_scatter(const float* __restrict__ tok,
                                                 const int* __restrict__ mem,
                                                 const int* __restrict__ grp,
                                                 float* __restrict__ xsum) {
    long tid = (long)blockIdx.x * 256 + threadIdx.x;
    int e = (int)(tid >> 6);
    int d = (int)(tid & 63);
    int m = mem[e];
    int g = grp[e];
    atomicAdd(&xsum[(size_t)g * 64 + d], tok[(size_t)m * 64 + d]);
}

// --------------------------- qp = cat(h[idx,src],h[idx,dst]) @ Wq^T + bq
// 64q x 64d tile per block; 256 threads; 4x4 outputs/thread; K=512 chunked by 32.
// aT/wT staged transposed -> inner loop = 2 ds_read_b128 per 16 FMA (VALU-bound).
__global__ __launch_bounds__(256) void k_qp2(const float* __restrict__ h,
                                             const float* __restrict__ Wq,
                                             const float* __restrict__ bq,
                                             const int* __restrict__ idx,
                                             const int* __restrict__ src,
                                             const int* __restrict__ dst,
                                             float* __restrict__ qp) {
    __shared__ float aT[32][68];   // [k][q], pad 68 for bank spread, 16B-aligned rows
    __shared__ float wT[32][68];   // [k][d]
    int qb = (blockIdx.x >> 2) << 6;
    int db = (blockIdx.x & 3) << 6;
    int t = threadIdx.x;
    int tq = t >> 4, td = t & 15;

    // hoisted gather metadata for the 2 staged q-rows this thread handles
    int qq0 = t >> 3, qq1 = (t + 256) >> 3;
    int g0 = qb + qq0, g1 = qb + qq1;
    int r0 = idx[g0], s0 = src[g0], e0 = dst[g0];
    int r1 = idx[g1], s1 = src[g1], e1 = dst[g1];
    int kk4a = (t & 7) << 2;   // same for both staged elements

    float acc[4][4] = {{0.f}};

    for (int c = 0; c < 16; c++) {
        int k0 = c << 5;
        int half = (k0 < 256);
        __syncthreads();
        {   // A: q_in[qb..qb+63][k0..k0+31], stored transposed
            const float* b0 = h + ((size_t)r0 * 64 + (half ? s0 : e0)) * 256 + (k0 & 255) + kk4a;
            const float* b1 = h + ((size_t)r1 * 64 + (half ? s1 : e1)) * 256 + (k0 & 255) + kk4a;
            float4 v0 = *(const float4*)b0;
            float4 v1 = *(const float4*)b1;
            aT[kk4a + 0][qq0] = v0.x; aT[kk4a + 1][qq0] = v0.y;
            aT[kk4a + 2][qq0] = v0.z; aT[kk4a + 3][qq0] = v0.w;
            aT[kk4a + 0][qq1] = v1.x; aT[kk4a + 1][qq1] = v1.y;
            aT[kk4a + 2][qq1] = v1.z; aT[kk4a + 3][qq1] = v1.w;
        }
        {   // B: Wq[db..db+63][k0..k0+31], stored transposed
            for (int i = t; i < 512; i += 256) {
                int dd = i >> 3, kk4 = (i & 7) << 2;
                float4 v = *(const float4*)(Wq + (size_t)(db + dd) * 512 + k0 + kk4);
                wT[kk4 + 0][dd] = v.x; wT[kk4 + 1][dd] = v.y;
                wT[kk4 + 2][dd] = v.z; wT[kk4 + 3][dd] = v.w;
            }
        }
        __syncthreads();
#pragma unroll 8
        for (int kk = 0; kk < 32; kk++) {
            float4 av = *(const float4*)&aT[kk][tq << 2];
            float4 wv = *(const float4*)&wT[kk][td << 2];
            acc[0][0] = fmaf(av.x, wv.x, acc[0][0]);
            acc[0][1] = fmaf(av.x, wv.y, acc[0][1]);
            acc[0][2] = fmaf(av.x, wv.z, acc[0][2]);
            acc[0][3] = fmaf(av.x, wv.w, acc[0][3]);
            acc[1][0] = fmaf(av.y, wv.x, acc[1][0]);
            acc[1][1] = fmaf(av.y, wv.y, acc[1][1]);
            acc[1][2] = fmaf(av.y, wv.z, acc[1][2]);
            acc[1][3] = fmaf(av.y, wv.w, acc[1][3]);
            acc[2][0] = fmaf(av.z, wv.x, acc[2][0]);
            acc[2][1] = fmaf(av.z, wv.y, acc[2][1]);
            acc[2][2] = fmaf(av.z, wv.z, acc[2][2]);
            acc[2][3] = fmaf(av.z, wv.w, acc[2][3]);
            acc[3][0] = fmaf(av.w, wv.x, acc[3][0]);
            acc[3][1] = fmaf(av.w, wv.y, acc[3][1]);
            acc[3][2] = fmaf(av.w, wv.z, acc[3][2]);
            acc[3][3] = fmaf(av.w, wv.w, acc[3][3]);
        }
    }

    int orow = qb + (tq << 2);
    int ocol = db + (td << 2);
    float b0 = bq[ocol], b1 = bq[ocol + 1], b2 = bq[ocol + 2], b3 = bq[ocol + 3];
#pragma unroll
    for (int i = 0; i < 4; i++) {
        float4 o = { acc[i][0] + b0, acc[i][1] + b1, acc[i][2] + b2, acc[i][3] + b3 };
        *(float4*)(qp + (size_t)(orow + i) * 256 + ocol) = o;
    }
}

// ------------------------------------------------------- qk = qp @ Wk
// same tiling; K=256; B read directly (contraction is Wk's row index)
__global__ __launch_bounds__(256) void k_qk2(const float* __restrict__ qp,
                                             const float* __restrict__ Wk,
                                             float* __restrict__ qk) {
    __shared__ float aT[32][68];   // [k][q]
    __shared__ float wS[32][68];   // [k][e] — direct layout, no transpose needed
    int qb = (blockIdx.x >> 2) << 6;
    int eb = (blockIdx.x & 3) << 6;
    int t = threadIdx.x;
    int tq = t >> 4, te = t & 15;

    int qq0 = t >> 3, qq1 = (t + 256) >> 3;
    int kk4a = (t & 7) << 2;

    float acc[4][4] = {{0.f}};

    for (int c = 0; c < 8; c++) {
        int k0 = c << 5;
        __syncthreads();
        {   // A: qp[qb..+63][k0..+31] transposed
            float4 v0 = *(const float4*)(qp + (size_t)(qb + qq0) * 256 + k0 + kk4a);
            float4 v1 = *(const float4*)(qp + (size_t)(qb + qq1) * 256 + k0 + kk4a);
            aT[kk4a + 0][qq0] = v0.x; aT[kk4a + 1][qq0] = v0.y;
            aT[kk4a + 2][qq0] = v0.z; aT[kk4a + 3][qq0] = v0.w;
            aT[kk4a + 0][qq1] = v1.x; aT[kk4a + 1][qq1] = v1.y;
            aT[kk4a + 2][qq1] = v1.z; aT[kk4a + 3][qq1] = v1.w;
        }
        {   // B: Wk[k0..+31][eb..+63] direct (float4 along e)
            for (int i = t; i < 512; i += 256) {
                int kk = i >> 4, ee4 = (i & 15) << 2;
                float4 v = *(const float4*)(Wk + (size_t)(k0 + kk) * 256 + eb + ee4);
                *(float4*)&wS[kk][ee4] = v;
            }
        }
        __syncthreads();
#pragma unroll 8
        for (int kk = 0; kk < 32; kk++) {
            float4 av = *(const float4*)&aT[kk][tq << 2];
            float4 wv = *(const float4*)&wS[kk][te << 2];
            acc[0][0] = fmaf(av.x, wv.x, acc[0][0]);
            acc[0][1] = fmaf(av.x, wv.y, acc[0][1]);
            acc[0][2] = fmaf(av.x, wv.z, acc[0][2]);
            acc[0][3] = fmaf(av.x, wv.w, acc[0][3]);
            acc[1][0] = fmaf(av.y, wv.x, acc[1][0]);
            acc[1][1] = fmaf(av.y, wv.y, acc[1][1]);
            acc[1][2] = fmaf(av.y, wv.z, acc[1][2]);
            acc[1][3] = fmaf(av.y, wv.w, acc[1][3]);
            acc[2][0] = fmaf(av.z, wv.x, acc[2][0]);
            acc[2][1] = fmaf(av.z, wv.y, acc[2][1]);
            acc[2][2] = fmaf(av.z, wv.z, acc[2][2]);
            acc[2][3] = fmaf(av.z, wv.w, acc[2][3]);
            acc[3][0] = fmaf(av.w, wv.x, acc[3][0]);
            acc[3][1] = fmaf(av.w, wv.y, acc[3][1]);
            acc[3][2] = fmaf(av.w, wv.z, acc[3][2]);
            acc[3][3] = fmaf(av.w, wv.w, acc[3][3]);
        }
    }

    int orow = qb + (tq << 2);
    int ocol = eb + (te << 2);
#pragma unroll
    for (int i = 0; i < 4; i++) {
        float4 o = { acc[i][0], acc[i][1], acc[i][2], acc[i][3] };
        *(float4*)(qk + (size_t)(orow + i) * 256 + ocol) = o;
    }
}

// ------------------------------------------------------ bterm[q] = bk . qp[q]
__global__ __launch_bounds__(256) void k_bterm(const float* __restrict__ qp,
                                               const float* __restrict__ bk,
                                               float* __restrict__ bterm) {
    int q = blockIdx.x * 4 + (threadIdx.x >> 6);
    int lane = threadIdx.x & 63;
    float4 v = *(const float4*)(qp + (size_t)q * 256 + lane * 4);
    float4 b = *(const float4*)(bk + lane * 4);
    float s = fmaf(v.x, b.x, fmaf(v.y, b.y, fmaf(v.z, b.z, v.w * b.w)));
#pragma unroll
    for (int off = 32; off; off >>= 1) s += __shfl_xor(s, off);
    if (lane == 0) bterm[q] = s;
}

// ------------------------------------ attention: one WAVE per query, no LDS
__global__ __launch_bounds__(256) void k_attn3(const float* __restrict__ h,
                                               const float* __restrict__ qk,
                                               const float* __restrict__ bterm,
                                               const float* __restrict__ xsum,
                                               const int* __restrict__ pos2grp,
                                               const int* __restrict__ msk,
                                               const int* __restrict__ idx,
                                               float* __restrict__ attn) {
    int wid  = threadIdx.x >> 6;
    int lane = threadIdx.x & 63;
    int q = blockIdx.x * 4 + wid;
    int row = idx[q];                       // wave-uniform -> scalar

    const float* hr  = h  + ((size_t)row * 64 + lane) * 256;
    const float* qkq = qk + (size_t)q * 256;   // wave-uniform -> scalar loads
    float p = 0.f;
#pragma unroll 4
    for (int j = 0; j < 256; j += 4) {
        float4 hv = *(const float4*)(hr + j);
        float4 qv = *(const float4*)(qkq + j);
        p = fmaf(hv.x, qv.x, fmaf(hv.y, qv.y,
            fmaf(hv.z, qv.z, fmaf(hv.w, qv.w, p))));
    }
    int v = msk[row * 64 + lane];
    float s = v ? (p + bterm[q]) * 0.0625f : -INFINITY;

    float m = s;
#pragma unroll
    for (int off = 32; off; off >>= 1) m = fmaxf(m, __shfl_xor(m, off));
    float e = expf(s - m);
    float sum = e;
#pragma unroll
    for (int off = 32; off; off >>= 1) sum += __shfl_xor(sum, off);
    float a = e / sum;

    const int* p2g = pos2grp + row * 64;
    float acc = 0.f;
#pragma unroll 8
    for (int l = 0; l < 64; l++) {
        float al = __shfl(a, l);
        int g = p2g[l];
        acc = fmaf(al, xsum[(size_t)g * 64 + lane], acc);
    }
    attn[(size_t)q * 64 + lane] = acc;
}

// --------------------------- logit = cat(q_in, attn) @ Wrel^T + brel ; metrics
#define VSTRIDE 580
__global__ __launch_bounds__(256) void k_logit(const float* __restrict__ h,
                                               const float* __restrict__ Wrel,
                                               const float* __restrict__ brel,
                                               const int* __restrict__ idx,
                                               const int* __restrict__ src,
                                               const int* __restrict__ dst,
                                               const float* __restrict__ attn,
                                               const int* __restrict__ typ,
                                               float* __restrict__ out,
                                               int* __restrict__ em,
                                               int* __restrict__ eqcnt) {
    __shared__ float vs[16 * VSTRIDE];
    __shared__ int cnt;
    int qb = blockIdx.x * 16;
    if (threadIdx.x == 0) cnt = 0;
    for (int i = threadIdx.x; i < 16 * 576; i += 256) {
        int qq = i / 576, j = i - qq * 576;
        int gq = qb + qq;
        float v;
        if (j < 512) {
            int r = idx[gq];
            int pos = (j < 256) ? src[gq] : dst[gq];
            v = h[((size_t)r * 64 + pos) * 256 + (j & 255)];
        } else {
            v = attn[(size_t)gq * 64 + (j - 512)];
        }
        vs[qq * VSTRIDE + j] = v;
    }
    __syncthreads();

    int qq = threadIdx.x >> 4, tt = threadIdx.x & 15;
    const float* wr = Wrel + (size_t)tt * 576;
    const float* vv = vs + qq * VSTRIDE;
    float acc = 0.f;
    for (int j = 0; j < 576; j += 4) {
        float4 wv = *(const float4*)(wr + j);
        float4 xv = *(const float4*)(vv + j);
        acc = fmaf(wv.x, xv.x, fmaf(wv.y, xv.y,
              fmaf(wv.z, xv.z, fmaf(wv.w, xv.w, acc))));
    }
    acc += brel[tt];
    int gq = qb + qq;
    out[(size_t)gq * 16 + tt] = acc;

    int eq = ((acc > 0.f) == (typ[gq * 16 + tt] > 0)) ? 1 : 0;
    unsigned long long mask = __ballot(eq);
    int lane = threadIdx.x & 63;
    if ((lane & 15) == 0) {
        unsigned bits = (unsigned)((mask >> (lane & 48)) & 0xFFFFull);
        atomicAdd(&cnt, __popc(bits));
        int all = (bits == 0xFFFFu) ? 1 : 0;
        atomicMin(&em[idx[gq]], all);
    }
    __syncthreads();
    if (threadIdx.x == 0) atomicAdd(eqcnt, cnt);
}

// ---------------------------------------------------------------- finalize
__global__ void k_fin(const int* __restrict__ em, const int* __restrict__ eqcnt,
                      float* __restrict__ out) {
    __shared__ float ssum[512];
    int t = threadIdx.x;
    int v = em[t];
    out[131074 + t] = (float)v;
    ssum[t] = (float)v;
    __syncthreads();
    for (int s = 256; s; s >>= 1) {
        if (t < s) ssum[t] += ssum[t + s];
        __syncthreads();
    }
    if (t == 0) {
        out[131073] = ssum[0] / 512.0f;
        out[131072] = (float)(*eqcnt) / (float)(Q_ * NTYP);
    }
}

extern "C" void kernel_launch(void* const* d_in, const int* in_sizes, int n_in,
                              void* d_out, int out_size, void* d_ws, size_t ws_size,
                              hipStream_t stream) {
    const float* h    = (const float*)d_in[0];
    const float* tok  = (const float*)d_in[1];
    const float* Wq   = (const float*)d_in[2];
    const float* bq   = (const float*)d_in[3];
    const float* Wk   = (const float*)d_in[4];
    const float* bk   = (const float*)d_in[5];
    const float* Wrel = (const float*)d_in[6];
    const float* brel = (const float*)d_in[7];
    const int* mem     = (const int*)d_in[8];
    const int* grp     = (const int*)d_in[9];
    const int* pos2grp = (const int*)d_in[10];
    const int* msk     = (const int*)d_in[11];
    const int* idx     = (const int*)d_in[12];
    const int* src     = (const int*)d_in[13];
    const int* dst     = (const int*)d_in[14];
    const int* typ     = (const int*)d_in[15];
    float* out = (float*)d_out;

    char* ws = (char*)d_ws;
    float* xsum  = (float*)ws;                          // 8 MB
    float* qk    = (float*)(ws + (size_t)( 8 << 20));   // 8 MB
    float* qp    = (float*)(ws + (size_t)(16 << 20));   // 8 MB
    float* bterm = (float*)(ws + (size_t)(24 << 20));   // 32 KB
    float* attn  = (float*)(ws + (size_t)(25 << 20));   // 2 MB
    int* em      = (int*)  (ws + (size_t)(27 << 20));   // 2 KB
    int* eqcnt   = (int*)  (ws + (size_t)(27 << 20) + 4096);

    hipMemsetAsync(xsum, 0, (size_t)NSEG * 64 * 4, stream);
    k_init<<<1, 512, 0, stream>>>(em, eqcnt);
    k_scatter<<<NMEM * 64 / 256, 256, 0, stream>>>(tok, mem, grp, xsum);
    k_qp2<<<(Q_ / 64) * 4, 256, 0, stream>>>(h, Wq, bq, idx, src, dst, qp);
    k_qk2<<<(Q_ / 64) * 4, 256, 0, stream>>>(qp, Wk, qk);
    k_bterm<<<Q_ / 4, 256, 0, stream>>>(qp, bk, bterm);
    k_attn3<<<Q_ / 4, 256, 0, stream>>>(h, qk, bterm, xsum, pos2grp, msk, idx, attn);
    k_logit<<<Q_ / 16, 256, 0, stream>>>(h, Wrel, brel, idx, src, dst, attn, typ, out, em, eqcnt);
    k_fin<<<1, 512, 0, stream>>>(em, eqcnt, out);
}

// Round 6
// 372.476 us; speedup vs baseline: 1.6175x; 1.0091x over previous
//
#include <hip/hip_runtime.h>
#include <math.h>

#define N_    512
#define L_    64
#define DH    256
#define DX    64
#define Q_    8192
#define NTYP  16
#define NMEM  262144
#define NSEG  32768

// ---------------------------------------------------------------- init
__global__ void k_init(int* __restrict__ em, int* __restrict__ eqcnt) {
    int t = blockIdx.x * blockDim.x + threadIdx.x;
    if (t < N_) em[t] = 0x7fffffff;   // segment_min identity (int32 max)
    if (t == 0) *eqcnt = 0;
}

// ---------------------------------------------------- segment scatter-sum
// x_sum[grp[e]][d] += tok_emb[mem[e]][d]; one wave = one edge (64 dims)
__global__ __launch_bounds__(256) void k_scatter(const float* __restrict__ tok,
                                                 const int* __restrict__ mem,
                                                 const int* __restrict__ grp,
                                                 float* __restrict__ xsum) {
    long tid = (long)blockIdx.x * 256 + threadIdx.x;
    int e = (int)(tid >> 6);
    int d = (int)(tid & 63);
    int m = mem[e];
    int g = grp[e];
    atomicAdd(&xsum[(size_t)g * 64 + d], tok[(size_t)m * 64 + d]);
}

// --------------------------- qp = cat(h[idx,src],h[idx,dst]) @ Wq^T + bq
// 64q x 64d tile per block; 256 threads; 4x4 outputs/thread; K=512 chunked by 32.
__global__ __launch_bounds__(256) void k_qp2(const float* __restrict__ h,
                                             const float* __restrict__ Wq,
                                             const float* __restrict__ bq,
                                             const int* __restrict__ idx,
                                             const int* __restrict__ src,
                                             const int* __restrict__ dst,
                                             float* __restrict__ qp) {
    __shared__ float aT[32][68];   // [k][q], pad 68 for bank spread
    __shared__ float wT[32][68];   // [k][d]
    int qb = (blockIdx.x >> 2) << 6;
    int db = (blockIdx.x & 3) << 6;
    int t = threadIdx.x;
    int tq = t >> 4, td = t & 15;

    int qq0 = t >> 3, qq1 = (t + 256) >> 3;
    int g0 = qb + qq0, g1 = qb + qq1;
    int r0 = idx[g0], s0 = src[g0], e0 = dst[g0];
    int r1 = idx[g1], s1 = src[g1], e1 = dst[g1];
    int kk4a = (t & 7) << 2;

    float acc[4][4] = {{0.f}};

    for (int c = 0; c < 16; c++) {
        int k0 = c << 5;
        int half = (k0 < 256);
        __syncthreads();
        {   // A: q_in[qb..qb+63][k0..k0+31], stored transposed
            const float* b0 = h + ((size_t)r0 * 64 + (half ? s0 : e0)) * 256 + (k0 & 255) + kk4a;
            const float* b1 = h + ((size_t)r1 * 64 + (half ? s1 : e1)) * 256 + (k0 & 255) + kk4a;
            float4 v0 = *(const float4*)b0;
            float4 v1 = *(const float4*)b1;
            aT[kk4a + 0][qq0] = v0.x; aT[kk4a + 1][qq0] = v0.y;
            aT[kk4a + 2][qq0] = v0.z; aT[kk4a + 3][qq0] = v0.w;
            aT[kk4a + 0][qq1] = v1.x; aT[kk4a + 1][qq1] = v1.y;
            aT[kk4a + 2][qq1] = v1.z; aT[kk4a + 3][qq1] = v1.w;
        }
        {   // B: Wq[db..db+63][k0..k0+31], stored transposed
            for (int i = t; i < 512; i += 256) {
                int dd = i >> 3, kk4 = (i & 7) << 2;
                float4 v = *(const float4*)(Wq + (size_t)(db + dd) * 512 + k0 + kk4);
                wT[kk4 + 0][dd] = v.x; wT[kk4 + 1][dd] = v.y;
                wT[kk4 + 2][dd] = v.z; wT[kk4 + 3][dd] = v.w;
            }
        }
        __syncthreads();
#pragma unroll 8
        for (int kk = 0; kk < 32; kk++) {
            float4 av = *(const float4*)&aT[kk][tq << 2];
            float4 wv = *(const float4*)&wT[kk][td << 2];
            acc[0][0] = fmaf(av.x, wv.x, acc[0][0]);
            acc[0][1] = fmaf(av.x, wv.y, acc[0][1]);
            acc[0][2] = fmaf(av.x, wv.z, acc[0][2]);
            acc[0][3] = fmaf(av.x, wv.w, acc[0][3]);
            acc[1][0] = fmaf(av.y, wv.x, acc[1][0]);
            acc[1][1] = fmaf(av.y, wv.y, acc[1][1]);
            acc[1][2] = fmaf(av.y, wv.z, acc[1][2]);
            acc[1][3] = fmaf(av.y, wv.w, acc[1][3]);
            acc[2][0] = fmaf(av.z, wv.x, acc[2][0]);
            acc[2][1] = fmaf(av.z, wv.y, acc[2][1]);
            acc[2][2] = fmaf(av.z, wv.z, acc[2][2]);
            acc[2][3] = fmaf(av.z, wv.w, acc[2][3]);
            acc[3][0] = fmaf(av.w, wv.x, acc[3][0]);
            acc[3][1] = fmaf(av.w, wv.y, acc[3][1]);
            acc[3][2] = fmaf(av.w, wv.z, acc[3][2]);
            acc[3][3] = fmaf(av.w, wv.w, acc[3][3]);
        }
    }

    int orow = qb + (tq << 2);
    int ocol = db + (td << 2);
    float b0 = bq[ocol], b1 = bq[ocol + 1], b2 = bq[ocol + 2], b3 = bq[ocol + 3];
#pragma unroll
    for (int i = 0; i < 4; i++) {
        float4 o = { acc[i][0] + b0, acc[i][1] + b1, acc[i][2] + b2, acc[i][3] + b3 };
        *(float4*)(qp + (size_t)(orow + i) * 256 + ocol) = o;
    }
}

// ------------------------------------------------------- qk = qp @ Wk
__global__ __launch_bounds__(256) void k_qk2(const float* __restrict__ qp,
                                             const float* __restrict__ Wk,
                                             float* __restrict__ qk) {
    __shared__ float aT[32][68];   // [k][q]
    __shared__ float wS[32][68];   // [k][e]
    int qb = (blockIdx.x >> 2) << 6;
    int eb = (blockIdx.x & 3) << 6;
    int t = threadIdx.x;
    int tq = t >> 4, te = t & 15;

    int qq0 = t >> 3, qq1 = (t + 256) >> 3;
    int kk4a = (t & 7) << 2;

    float acc[4][4] = {{0.f}};

    for (int c = 0; c < 8; c++) {
        int k0 = c << 5;
        __syncthreads();
        {
            float4 v0 = *(const float4*)(qp + (size_t)(qb + qq0) * 256 + k0 + kk4a);
            float4 v1 = *(const float4*)(qp + (size_t)(qb + qq1) * 256 + k0 + kk4a);
            aT[kk4a + 0][qq0] = v0.x; aT[kk4a + 1][qq0] = v0.y;
            aT[kk4a + 2][qq0] = v0.z; aT[kk4a + 3][qq0] = v0.w;
            aT[kk4a + 0][qq1] = v1.x; aT[kk4a + 1][qq1] = v1.y;
            aT[kk4a + 2][qq1] = v1.z; aT[kk4a + 3][qq1] = v1.w;
        }
        {
            for (int i = t; i < 512; i += 256) {
                int kk = i >> 4, ee4 = (i & 15) << 2;
                float4 v = *(const float4*)(Wk + (size_t)(k0 + kk) * 256 + eb + ee4);
                *(float4*)&wS[kk][ee4] = v;
            }
        }
        __syncthreads();
#pragma unroll 8
        for (int kk = 0; kk < 32; kk++) {
            float4 av = *(const float4*)&aT[kk][tq << 2];
            float4 wv = *(const float4*)&wS[kk][te << 2];
            acc[0][0] = fmaf(av.x, wv.x, acc[0][0]);
            acc[0][1] = fmaf(av.x, wv.y, acc[0][1]);
            acc[0][2] = fmaf(av.x, wv.z, acc[0][2]);
            acc[0][3] = fmaf(av.x, wv.w, acc[0][3]);
            acc[1][0] = fmaf(av.y, wv.x, acc[1][0]);
            acc[1][1] = fmaf(av.y, wv.y, acc[1][1]);
            acc[1][2] = fmaf(av.y, wv.z, acc[1][2]);
            acc[1][3] = fmaf(av.y, wv.w, acc[1][3]);
            acc[2][0] = fmaf(av.z, wv.x, acc[2][0]);
            acc[2][1] = fmaf(av.z, wv.y, acc[2][1]);
            acc[2][2] = fmaf(av.z, wv.z, acc[2][2]);
            acc[2][3] = fmaf(av.z, wv.w, acc[2][3]);
            acc[3][0] = fmaf(av.w, wv.x, acc[3][0]);
            acc[3][1] = fmaf(av.w, wv.y, acc[3][1]);
            acc[3][2] = fmaf(av.w, wv.z, acc[3][2]);
            acc[3][3] = fmaf(av.w, wv.w, acc[3][3]);
        }
    }

    int orow = qb + (tq << 2);
    int ocol = eb + (te << 2);
#pragma unroll
    for (int i = 0; i < 4; i++) {
        float4 o = { acc[i][0], acc[i][1], acc[i][2], acc[i][3] };
        *(float4*)(qk + (size_t)(orow + i) * 256 + ocol) = o;
    }
}

// ------------------------------------------------------ bterm[q] = bk . qp[q]
__global__ __launch_bounds__(256) void k_bterm(const float* __restrict__ qp,
                                               const float* __restrict__ bk,
                                               float* __restrict__ bterm) {
    int q = blockIdx.x * 4 + (threadIdx.x >> 6);
    int lane = threadIdx.x & 63;
    float4 v = *(const float4*)(qp + (size_t)q * 256 + lane * 4);
    float4 b = *(const float4*)(bk + lane * 4);
    float s = fmaf(v.x, b.x, fmaf(v.y, b.y, fmaf(v.z, b.z, v.w * b.w)));
#pragma unroll
    for (int off = 32; off; off >>= 1) s += __shfl_xor(s, off);
    if (lane == 0) bterm[q] = s;
}

// ------------------------------------ attention: one WAVE per query, no LDS
// XCD-aware chunked swizzle: queries are sorted by row; 4 adjacent blocks share
// one 64KB h-row. Default dispatch round-robins adjacent blocks over 8 XCDs ->
// each XCD L2 refetches the row from HBM (FETCH ~100MB vs ~48MB unique).
// Remap so each XCD owns 256 contiguous blocks (=1024 sorted queries, ~4MB of h).
__global__ __launch_bounds__(256) void k_attn3(const float* __restrict__ h,
                                               const float* __restrict__ qk,
                                               const float* __restrict__ bterm,
                                               const float* __restrict__ xsum,
                                               const int* __restrict__ pos2grp,
                                               const int* __restrict__ msk,
                                               const int* __restrict__ idx,
                                               float* __restrict__ attn) {
    int wid  = threadIdx.x >> 6;
    int lane = threadIdx.x & 63;
    int bid = ((blockIdx.x & 7) << 8) | (blockIdx.x >> 3);   // 2048 = 8 XCD * 256
    int q = bid * 4 + wid;
    int row = idx[q];                       // wave-uniform -> scalar

    const float* hr  = h  + ((size_t)row * 64 + lane) * 256;
    const float* qkq = qk + (size_t)q * 256;   // wave-uniform -> scalar loads
    float p = 0.f;
#pragma unroll 4
    for (int j = 0; j < 256; j += 4) {
        float4 hv = *(const float4*)(hr + j);
        float4 qv = *(const float4*)(qkq + j);
        p = fmaf(hv.x, qv.x, fmaf(hv.y, qv.y,
            fmaf(hv.z, qv.z, fmaf(hv.w, qv.w, p))));
    }
    int v = msk[row * 64 + lane];
    float s = v ? (p + bterm[q]) * 0.0625f : -INFINITY;

    float m = s;
#pragma unroll
    for (int off = 32; off; off >>= 1) m = fmaxf(m, __shfl_xor(m, off));
    float e = expf(s - m);
    float sum = e;
#pragma unroll
    for (int off = 32; off; off >>= 1) sum += __shfl_xor(sum, off);
    float a = e / sum;

    const int* p2g = pos2grp + row * 64;
    float acc = 0.f;
#pragma unroll 8
    for (int l = 0; l < 64; l++) {
        float al = __shfl(a, l);
        int g = p2g[l];
        acc = fmaf(al, xsum[(size_t)g * 64 + lane], acc);
    }
    attn[(size_t)q * 64 + lane] = acc;
}

// --------------------------- logit = cat(q_in, attn) @ Wrel^T + brel ; metrics
#define VSTRIDE 580
__global__ __launch_bounds__(256) void k_logit(const float* __restrict__ h,
                                               const float* __restrict__ Wrel,
                                               const float* __restrict__ brel,
                                               const int* __restrict__ idx,
                                               const int* __restrict__ src,
                                               const int* __restrict__ dst,
                                               const float* __restrict__ attn,
                                               const int* __restrict__ typ,
                                               float* __restrict__ out,
                                               int* __restrict__ em,
                                               int* __restrict__ eqcnt) {
    __shared__ float vs[16 * VSTRIDE];
    __shared__ int cnt;
    int qb = blockIdx.x * 16;
    if (threadIdx.x == 0) cnt = 0;
    for (int i = threadIdx.x; i < 16 * 576; i += 256) {
        int qq = i / 576, j = i - qq * 576;
        int gq = qb + qq;
        float v;
        if (j < 512) {
            int r = idx[gq];
            int pos = (j < 256) ? src[gq] : dst[gq];
            v = h[((size_t)r * 64 + pos) * 256 + (j & 255)];
        } else {
            v = attn[(size_t)gq * 64 + (j - 512)];
        }
        vs[qq * VSTRIDE + j] = v;
    }
    __syncthreads();

    int qq = threadIdx.x >> 4, tt = threadIdx.x & 15;
    const float* wr = Wrel + (size_t)tt * 576;
    const float* vv = vs + qq * VSTRIDE;
    float acc = 0.f;
    for (int j = 0; j < 576; j += 4) {
        float4 wv = *(const float4*)(wr + j);
        float4 xv = *(const float4*)(vv + j);
        acc = fmaf(wv.x, xv.x, fmaf(wv.y, xv.y,
              fmaf(wv.z, xv.z, fmaf(wv.w, xv.w, acc))));
    }
    acc += brel[tt];
    int gq = qb + qq;
    out[(size_t)gq * 16 + tt] = acc;

    int eq = ((acc > 0.f) == (typ[gq * 16 + tt] > 0)) ? 1 : 0;
    unsigned long long mask = __ballot(eq);
    int lane = threadIdx.x & 63;
    if ((lane & 15) == 0) {
        unsigned bits = (unsigned)((mask >> (lane & 48)) & 0xFFFFull);
        atomicAdd(&cnt, __popc(bits));
        int all = (bits == 0xFFFFu) ? 1 : 0;
        atomicMin(&em[idx[gq]], all);
    }
    __syncthreads();
    if (threadIdx.x == 0) atomicAdd(eqcnt, cnt);
}

// ---------------------------------------------------------------- finalize
__global__ void k_fin(const int* __restrict__ em, const int* __restrict__ eqcnt,
                      float* __restrict__ out) {
    __shared__ float ssum[512];
    int t = threadIdx.x;
    int v = em[t];
    out[131074 + t] = (float)v;
    ssum[t] = (float)v;
    __syncthreads();
    for (int s = 256; s; s >>= 1) {
        if (t < s) ssum[t] += ssum[t + s];
        __syncthreads();
    }
    if (t == 0) {
        out[131073] = ssum[0] / 512.0f;
        out[131072] = (float)(*eqcnt) / (float)(Q_ * NTYP);
    }
}

extern "C" void kernel_launch(void* const* d_in, const int* in_sizes, int n_in,
                              void* d_out, int out_size, void* d_ws, size_t ws_size,
                              hipStream_t stream) {
    const float* h    = (const float*)d_in[0];
    const float* tok  = (const float*)d_in[1];
    const float* Wq   = (const float*)d_in[2];
    const float* bq   = (const float*)d_in[3];
    const float* Wk   = (const float*)d_in[4];
    const float* bk   = (const float*)d_in[5];
    const float* Wrel = (const float*)d_in[6];
    const float* brel = (const float*)d_in[7];
    const int* mem     = (const int*)d_in[8];
    const int* grp     = (const int*)d_in[9];
    const int* pos2grp = (const int*)d_in[10];
    const int* msk     = (const int*)d_in[11];
    const int* idx     = (const int*)d_in[12];
    const int* src     = (const int*)d_in[13];
    const int* dst     = (const int*)d_in[14];
    const int* typ     = (const int*)d_in[15];
    float* out = (float*)d_out;

    char* ws = (char*)d_ws;
    float* xsum  = (float*)ws;                          // 8 MB
    float* qk    = (float*)(ws + (size_t)( 8 << 20));   // 8 MB
    float* qp    = (float*)(ws + (size_t)(16 << 20));   // 8 MB
    float* bterm = (float*)(ws + (size_t)(24 << 20));   // 32 KB
    float* attn  = (float*)(ws + (size_t)(25 << 20));   // 2 MB
    int* em      = (int*)  (ws + (size_t)(27 << 20));   // 2 KB
    int* eqcnt   = (int*)  (ws + (size_t)(27 << 20) + 4096);

    hipMemsetAsync(xsum, 0, (size_t)NSEG * 64 * 4, stream);
    k_init<<<1, 512, 0, stream>>>(em, eqcnt);
    k_scatter<<<NMEM * 64 / 256, 256, 0, stream>>>(tok, mem, grp, xsum);
    k_qp2<<<(Q_ / 64) * 4, 256, 0, stream>>>(h, Wq, bq, idx, src, dst, qp);
    k_qk2<<<(Q_ / 64) * 4, 256, 0, stream>>>(qp, Wk, qk);
    k_bterm<<<Q_ / 4, 256, 0, stream>>>(qp, bk, bterm);
    k_attn3<<<Q_ / 4, 256, 0, stream>>>(h, qk, bterm, xsum, pos2grp, msk, idx, attn);
    k_logit<<<Q_ / 16, 256, 0, stream>>>(h, Wrel, brel, idx, src, dst, attn, typ, out, em, eqcnt);
    k_fin<<<1, 512, 0, stream>>>(em, eqcnt, out);
}

// Round 7
// 338.443 us; speedup vs baseline: 1.7802x; 1.1006x over previous
//
#include <hip/hip_runtime.h>
#include <math.h>

#define N_    512
#define L_    64
#define DH    256
#define DX    64
#define Q_    8192
#define NTYP  16
#define NMEM  262144
#define NSEG  32768

// ---------------------------------------------------------------- init
__global__ void k_init(int* __restrict__ em, int* __restrict__ eqcnt) {
    int t = blockIdx.x * blockDim.x + threadIdx.x;
    if (t < N_) em[t] = 0x7fffffff;   // segment_min identity (int32 max)
    if (t == 0) *eqcnt = 0;
}

// ---------------------------------------------------- segment scatter-sum
__global__ __launch_bounds__(256) void k_scatter(const float* __restrict__ tok,
                                                 const int* __restrict__ mem,
                                                 const int* __restrict__ grp,
                                                 float* __restrict__ xsum) {
    long tid = (long)blockIdx.x * 256 + threadIdx.x;
    int e = (int)(tid >> 6);
    int d = (int)(tid & 63);
    int m = mem[e];
    int g = grp[e];
    atomicAdd(&xsum[(size_t)g * 64 + d], tok[(size_t)m * 64 + d]);
}

// --------------------------- qp = cat(h[idx,src],h[idx,dst]) @ Wq^T + bq
__global__ __launch_bounds__(256) void k_qp2(const float* __restrict__ h,
                                             const float* __restrict__ Wq,
                                             const float* __restrict__ bq,
                                             const int* __restrict__ idx,
                                             const int* __restrict__ src,
                                             const int* __restrict__ dst,
                                             float* __restrict__ qp) {
    __shared__ float aT[32][68];
    __shared__ float wT[32][68];
    int qb = (blockIdx.x >> 2) << 6;
    int db = (blockIdx.x & 3) << 6;
    int t = threadIdx.x;
    int tq = t >> 4, td = t & 15;

    int qq0 = t >> 3, qq1 = (t + 256) >> 3;
    int g0 = qb + qq0, g1 = qb + qq1;
    int r0 = idx[g0], s0 = src[g0], e0 = dst[g0];
    int r1 = idx[g1], s1 = src[g1], e1 = dst[g1];
    int kk4a = (t & 7) << 2;

    float acc[4][4] = {{0.f}};

    for (int c = 0; c < 16; c++) {
        int k0 = c << 5;
        int half = (k0 < 256);
        __syncthreads();
        {
            const float* b0 = h + ((size_t)r0 * 64 + (half ? s0 : e0)) * 256 + (k0 & 255) + kk4a;
            const float* b1 = h + ((size_t)r1 * 64 + (half ? s1 : e1)) * 256 + (k0 & 255) + kk4a;
            float4 v0 = *(const float4*)b0;
            float4 v1 = *(const float4*)b1;
            aT[kk4a + 0][qq0] = v0.x; aT[kk4a + 1][qq0] = v0.y;
            aT[kk4a + 2][qq0] = v0.z; aT[kk4a + 3][qq0] = v0.w;
            aT[kk4a + 0][qq1] = v1.x; aT[kk4a + 1][qq1] = v1.y;
            aT[kk4a + 2][qq1] = v1.z; aT[kk4a + 3][qq1] = v1.w;
        }
        {
            for (int i = t; i < 512; i += 256) {
                int dd = i >> 3, kk4 = (i & 7) << 2;
                float4 v = *(const float4*)(Wq + (size_t)(db + dd) * 512 + k0 + kk4);
                wT[kk4 + 0][dd] = v.x; wT[kk4 + 1][dd] = v.y;
                wT[kk4 + 2][dd] = v.z; wT[kk4 + 3][dd] = v.w;
            }
        }
        __syncthreads();
#pragma unroll 8
        for (int kk = 0; kk < 32; kk++) {
            float4 av = *(const float4*)&aT[kk][tq << 2];
            float4 wv = *(const float4*)&wT[kk][td << 2];
            acc[0][0] = fmaf(av.x, wv.x, acc[0][0]);
            acc[0][1] = fmaf(av.x, wv.y, acc[0][1]);
            acc[0][2] = fmaf(av.x, wv.z, acc[0][2]);
            acc[0][3] = fmaf(av.x, wv.w, acc[0][3]);
            acc[1][0] = fmaf(av.y, wv.x, acc[1][0]);
            acc[1][1] = fmaf(av.y, wv.y, acc[1][1]);
            acc[1][2] = fmaf(av.y, wv.z, acc[1][2]);
            acc[1][3] = fmaf(av.y, wv.w, acc[1][3]);
            acc[2][0] = fmaf(av.z, wv.x, acc[2][0]);
            acc[2][1] = fmaf(av.z, wv.y, acc[2][1]);
            acc[2][2] = fmaf(av.z, wv.z, acc[2][2]);
            acc[2][3] = fmaf(av.z, wv.w, acc[2][3]);
            acc[3][0] = fmaf(av.w, wv.x, acc[3][0]);
            acc[3][1] = fmaf(av.w, wv.y, acc[3][1]);
            acc[3][2] = fmaf(av.w, wv.z, acc[3][2]);
            acc[3][3] = fmaf(av.w, wv.w, acc[3][3]);
        }
    }

    int orow = qb + (tq << 2);
    int ocol = db + (td << 2);
    float b0 = bq[ocol], b1 = bq[ocol + 1], b2 = bq[ocol + 2], b3 = bq[ocol + 3];
#pragma unroll
    for (int i = 0; i < 4; i++) {
        float4 o = { acc[i][0] + b0, acc[i][1] + b1, acc[i][2] + b2, acc[i][3] + b3 };
        *(float4*)(qp + (size_t)(orow + i) * 256 + ocol) = o;
    }
}

// ------------------------------------------------------- qk = qp @ Wk
__global__ __launch_bounds__(256) void k_qk2(const float* __restrict__ qp,
                                             const float* __restrict__ Wk,
                                             float* __restrict__ qk) {
    __shared__ float aT[32][68];
    __shared__ float wS[32][68];
    int qb = (blockIdx.x >> 2) << 6;
    int eb = (blockIdx.x & 3) << 6;
    int t = threadIdx.x;
    int tq = t >> 4, te = t & 15;

    int qq0 = t >> 3, qq1 = (t + 256) >> 3;
    int kk4a = (t & 7) << 2;

    float acc[4][4] = {{0.f}};

    for (int c = 0; c < 8; c++) {
        int k0 = c << 5;
        __syncthreads();
        {
            float4 v0 = *(const float4*)(qp + (size_t)(qb + qq0) * 256 + k0 + kk4a);
            float4 v1 = *(const float4*)(qp + (size_t)(qb + qq1) * 256 + k0 + kk4a);
            aT[kk4a + 0][qq0] = v0.x; aT[kk4a + 1][qq0] = v0.y;
            aT[kk4a + 2][qq0] = v0.z; aT[kk4a + 3][qq0] = v0.w;
            aT[kk4a + 0][qq1] = v1.x; aT[kk4a + 1][qq1] = v1.y;
            aT[kk4a + 2][qq1] = v1.z; aT[kk4a + 3][qq1] = v1.w;
        }
        {
            for (int i = t; i < 512; i += 256) {
                int kk = i >> 4, ee4 = (i & 15) << 2;
                float4 v = *(const float4*)(Wk + (size_t)(k0 + kk) * 256 + eb + ee4);
                *(float4*)&wS[kk][ee4] = v;
            }
        }
        __syncthreads();
#pragma unroll 8
        for (int kk = 0; kk < 32; kk++) {
            float4 av = *(const float4*)&aT[kk][tq << 2];
            float4 wv = *(const float4*)&wS[kk][te << 2];
            acc[0][0] = fmaf(av.x, wv.x, acc[0][0]);
            acc[0][1] = fmaf(av.x, wv.y, acc[0][1]);
            acc[0][2] = fmaf(av.x, wv.z, acc[0][2]);
            acc[0][3] = fmaf(av.x, wv.w, acc[0][3]);
            acc[1][0] = fmaf(av.y, wv.x, acc[1][0]);
            acc[1][1] = fmaf(av.y, wv.y, acc[1][1]);
            acc[1][2] = fmaf(av.y, wv.z, acc[1][2]);
            acc[1][3] = fmaf(av.y, wv.w, acc[1][3]);
            acc[2][0] = fmaf(av.z, wv.x, acc[2][0]);
            acc[2][1] = fmaf(av.z, wv.y, acc[2][1]);
            acc[2][2] = fmaf(av.z, wv.z, acc[2][2]);
            acc[2][3] = fmaf(av.z, wv.w, acc[2][3]);
            acc[3][0] = fmaf(av.w, wv.x, acc[3][0]);
            acc[3][1] = fmaf(av.w, wv.y, acc[3][1]);
            acc[3][2] = fmaf(av.w, wv.z, acc[3][2]);
            acc[3][3] = fmaf(av.w, wv.w, acc[3][3]);
        }
    }

    int orow = qb + (tq << 2);
    int ocol = eb + (te << 2);
#pragma unroll
    for (int i = 0; i < 4; i++) {
        float4 o = { acc[i][0], acc[i][1], acc[i][2], acc[i][3] };
        *(float4*)(qk + (size_t)(orow + i) * 256 + ocol) = o;
    }
}

// ------------------------------------------------------ bterm[q] = bk . qp[q]
__global__ __launch_bounds__(256) void k_bterm(const float* __restrict__ qp,
                                               const float* __restrict__ bk,
                                               float* __restrict__ bterm) {
    int q = blockIdx.x * 4 + (threadIdx.x >> 6);
    int lane = threadIdx.x & 63;
    float4 v = *(const float4*)(qp + (size_t)q * 256 + lane * 4);
    float4 b = *(const float4*)(bk + lane * 4);
    float s = fmaf(v.x, b.x, fmaf(v.y, b.y, fmaf(v.z, b.z, v.w * b.w)));
#pragma unroll
    for (int off = 32; off; off >>= 1) s += __shfl_xor(s, off);
    if (lane == 0) bterm[q] = s;
}

// -------------------- h transpose: hT4[row][j4][l] = (float4)h[row][l][4j4..4j4+3]
// LDS-tiled so both global sides are coalesced. One block per row.
__global__ __launch_bounds__(256) void k_htr(const float* __restrict__ h,
                                             float4* __restrict__ hT4) {
    __shared__ float hsT[256][65];   // [d][l], pad 65 -> conflict-free reads
    int row = blockIdx.x;
    int t = threadIdx.x;
    const float4* h4 = (const float4*)(h + (size_t)row * 64 * 256);
    for (int i = t; i < 4096; i += 256) {          // coalesced global read
        int l = i >> 6, d4 = i & 63;
        float4 v = h4[i];
        hsT[d4 * 4 + 0][l] = v.x; hsT[d4 * 4 + 1][l] = v.y;
        hsT[d4 * 4 + 2][l] = v.z; hsT[d4 * 4 + 3][l] = v.w;
    }
    __syncthreads();
    float4* o4 = hT4 + (size_t)row * 4096;
    for (int i = t; i < 4096; i += 256) {          // coalesced global write
        int j4 = i >> 6, l = i & 63;
        float4 o = { hsT[4 * j4 + 0][l], hsT[4 * j4 + 1][l],
                     hsT[4 * j4 + 2][l], hsT[4 * j4 + 3][l] };
        o4[i] = o;
    }
}

// ------------------------------------ attention v4: wave per query, COALESCED h
// phase A reads hT4[row][j4][lane]: 64 lanes = 1KB contiguous per instr
// (16 cache lines vs 64 for the strided h layout -> 4x less L1/TA line traffic).
__global__ __launch_bounds__(256) void k_attn4(const float4* __restrict__ hT4,
                                               const float* __restrict__ qk,
                                               const float* __restrict__ bterm,
                                               const float* __restrict__ xsum,
                                               const int* __restrict__ pos2grp,
                                               const int* __restrict__ msk,
                                               const int* __restrict__ idx,
                                               float* __restrict__ attn) {
    int wid  = threadIdx.x >> 6;
    int lane = threadIdx.x & 63;
    int bid = ((blockIdx.x & 7) << 8) | (blockIdx.x >> 3);   // XCD chunked swizzle
    int q = bid * 4 + wid;
    int row = idx[q];

    const float4* hT  = hT4 + (size_t)row * 4096;            // [j4][l]
    const float4* qk4 = (const float4*)(qk + (size_t)q * 256);  // wave-uniform
    float p = 0.f;
#pragma unroll 8
    for (int j4 = 0; j4 < 64; j4++) {
        float4 hv = hT[j4 * 64 + lane];                      // coalesced 1KB
        float4 qv = qk4[j4];
        p = fmaf(hv.x, qv.x, fmaf(hv.y, qv.y,
            fmaf(hv.z, qv.z, fmaf(hv.w, qv.w, p))));
    }
    int v = msk[row * 64 + lane];
    float s = v ? (p + bterm[q]) * 0.0625f : -INFINITY;

    float m = s;
#pragma unroll
    for (int off = 32; off; off >>= 1) m = fmaxf(m, __shfl_xor(m, off));
    float e = expf(s - m);
    float sum = e;
#pragma unroll
    for (int off = 32; off; off >>= 1) sum += __shfl_xor(sum, off);
    float a = e / sum;

    int g_l = pos2grp[row * 64 + lane];                      // coalesced once
    float acc = 0.f;
#pragma unroll 8
    for (int l = 0; l < 64; l++) {
        float al = __shfl(a, l);
        int g = __shfl(g_l, l);
        acc = fmaf(al, xsum[(size_t)g * 64 + lane], acc);    // coalesced 256B
    }
    attn[(size_t)q * 64 + lane] = acc;
}

// ------------------------------------ attention v3 (fallback if ws too small)
__global__ __launch_bounds__(256) void k_attn3(const float* __restrict__ h,
                                               const float* __restrict__ qk,
                                               const float* __restrict__ bterm,
                                               const float* __restrict__ xsum,
                                               const int* __restrict__ pos2grp,
                                               const int* __restrict__ msk,
                                               const int* __restrict__ idx,
                                               float* __restrict__ attn) {
    int wid  = threadIdx.x >> 6;
    int lane = threadIdx.x & 63;
    int bid = ((blockIdx.x & 7) << 8) | (blockIdx.x >> 3);
    int q = bid * 4 + wid;
    int row = idx[q];

    const float* hr  = h  + ((size_t)row * 64 + lane) * 256;
    const float* qkq = qk + (size_t)q * 256;
    float p = 0.f;
#pragma unroll 4
    for (int j = 0; j < 256; j += 4) {
        float4 hv = *(const float4*)(hr + j);
        float4 qv = *(const float4*)(qkq + j);
        p = fmaf(hv.x, qv.x, fmaf(hv.y, qv.y,
            fmaf(hv.z, qv.z, fmaf(hv.w, qv.w, p))));
    }
    int v = msk[row * 64 + lane];
    float s = v ? (p + bterm[q]) * 0.0625f : -INFINITY;

    float m = s;
#pragma unroll
    for (int off = 32; off; off >>= 1) m = fmaxf(m, __shfl_xor(m, off));
    float e = expf(s - m);
    float sum = e;
#pragma unroll
    for (int off = 32; off; off >>= 1) sum += __shfl_xor(sum, off);
    float a = e / sum;

    const int* p2g = pos2grp + row * 64;
    float acc = 0.f;
#pragma unroll 8
    for (int l = 0; l < 64; l++) {
        float al = __shfl(a, l);
        int g = p2g[l];
        acc = fmaf(al, xsum[(size_t)g * 64 + lane], acc);
    }
    attn[(size_t)q * 64 + lane] = acc;
}

// --------------------------- logit = cat(q_in, attn) @ Wrel^T + brel ; metrics
#define VSTRIDE 580
__global__ __launch_bounds__(256) void k_logit(const float* __restrict__ h,
                                               const float* __restrict__ Wrel,
                                               const float* __restrict__ brel,
                                               const int* __restrict__ idx,
                                               const int* __restrict__ src,
                                               const int* __restrict__ dst,
                                               const float* __restrict__ attn,
                                               const int* __restrict__ typ,
                                               float* __restrict__ out,
                                               int* __restrict__ em,
                                               int* __restrict__ eqcnt) {
    __shared__ float vs[16 * VSTRIDE];
    __shared__ int cnt;
    int qb = blockIdx.x * 16;
    if (threadIdx.x == 0) cnt = 0;
    for (int i = threadIdx.x; i < 16 * 576; i += 256) {
        int qq = i / 576, j = i - qq * 576;
        int gq = qb + qq;
        float v;
        if (j < 512) {
            int r = idx[gq];
            int pos = (j < 256) ? src[gq] : dst[gq];
            v = h[((size_t)r * 64 + pos) * 256 + (j & 255)];
        } else {
            v = attn[(size_t)gq * 64 + (j - 512)];
        }
        vs[qq * VSTRIDE + j] = v;
    }
    __syncthreads();

    int qq = threadIdx.x >> 4, tt = threadIdx.x & 15;
    const float* wr = Wrel + (size_t)tt * 576;
    const float* vv = vs + qq * VSTRIDE;
    float acc = 0.f;
    for (int j = 0; j < 576; j += 4) {
        float4 wv = *(const float4*)(wr + j);
        float4 xv = *(const float4*)(vv + j);
        acc = fmaf(wv.x, xv.x, fmaf(wv.y, xv.y,
              fmaf(wv.z, xv.z, fmaf(wv.w, xv.w, acc))));
    }
    acc += brel[tt];
    int gq = qb + qq;
    out[(size_t)gq * 16 + tt] = acc;

    int eq = ((acc > 0.f) == (typ[gq * 16 + tt] > 0)) ? 1 : 0;
    unsigned long long mask = __ballot(eq);
    int lane = threadIdx.x & 63;
    if ((lane & 15) == 0) {
        unsigned bits = (unsigned)((mask >> (lane & 48)) & 0xFFFFull);
        atomicAdd(&cnt, __popc(bits));
        int all = (bits == 0xFFFFu) ? 1 : 0;
        atomicMin(&em[idx[gq]], all);
    }
    __syncthreads();
    if (threadIdx.x == 0) atomicAdd(eqcnt, cnt);
}

// ---------------------------------------------------------------- finalize
__global__ void k_fin(const int* __restrict__ em, const int* __restrict__ eqcnt,
                      float* __restrict__ out) {
    __shared__ float ssum[512];
    int t = threadIdx.x;
    int v = em[t];
    out[131074 + t] = (float)v;
    ssum[t] = (float)v;
    __syncthreads();
    for (int s = 256; s; s >>= 1) {
        if (t < s) ssum[t] += ssum[t + s];
        __syncthreads();
    }
    if (t == 0) {
        out[131073] = ssum[0] / 512.0f;
        out[131072] = (float)(*eqcnt) / (float)(Q_ * NTYP);
    }
}

extern "C" void kernel_launch(void* const* d_in, const int* in_sizes, int n_in,
                              void* d_out, int out_size, void* d_ws, size_t ws_size,
                              hipStream_t stream) {
    const float* h    = (const float*)d_in[0];
    const float* tok  = (const float*)d_in[1];
    const float* Wq   = (const float*)d_in[2];
    const float* bq   = (const float*)d_in[3];
    const float* Wk   = (const float*)d_in[4];
    const float* bk   = (const float*)d_in[5];
    const float* Wrel = (const float*)d_in[6];
    const float* brel = (const float*)d_in[7];
    const int* mem     = (const int*)d_in[8];
    const int* grp     = (const int*)d_in[9];
    const int* pos2grp = (const int*)d_in[10];
    const int* msk     = (const int*)d_in[11];
    const int* idx     = (const int*)d_in[12];
    const int* src     = (const int*)d_in[13];
    const int* dst     = (const int*)d_in[14];
    const int* typ     = (const int*)d_in[15];
    float* out = (float*)d_out;

    char* ws = (char*)d_ws;
    float* xsum  = (float*)ws;                          // 8 MB
    float* qk    = (float*)(ws + (size_t)( 8 << 20));   // 8 MB
    float* qp    = (float*)(ws + (size_t)(16 << 20));   // 8 MB
    float* bterm = (float*)(ws + (size_t)(24 << 20));   // 32 KB
    float* attn  = (float*)(ws + (size_t)(25 << 20));   // 2 MB
    int* em      = (int*)  (ws + (size_t)(27 << 20));   // 2 KB
    int* eqcnt   = (int*)  (ws + (size_t)(27 << 20) + 4096);
    float4* hT4  = (float4*)(ws + (size_t)(28 << 20));  // 32 MB
    bool use_tr  = ws_size >= ((size_t)(28 << 20) + (size_t)(32 << 20));

    hipMemsetAsync(xsum, 0, (size_t)NSEG * 64 * 4, stream);
    k_init<<<1, 512, 0, stream>>>(em, eqcnt);
    k_scatter<<<NMEM * 64 / 256, 256, 0, stream>>>(tok, mem, grp, xsum);
    k_qp2<<<(Q_ / 64) * 4, 256, 0, stream>>>(h, Wq, bq, idx, src, dst, qp);
    k_qk2<<<(Q_ / 64) * 4, 256, 0, stream>>>(qp, Wk, qk);
    k_bterm<<<Q_ / 4, 256, 0, stream>>>(qp, bk, bterm);
    if (use_tr) {
        k_htr<<<N_, 256, 0, stream>>>(h, hT4);
        k_attn4<<<Q_ / 4, 256, 0, stream>>>(hT4, qk, bterm, xsum, pos2grp, msk, idx, attn);
    } else {
        k_attn3<<<Q_ / 4, 256, 0, stream>>>(h, qk, bterm, xsum, pos2grp, msk, idx, attn);
    }
    k_logit<<<Q_ / 16, 256, 0, stream>>>(h, Wrel, brel, idx, src, dst, attn, typ, out, em, eqcnt);
    k_fin<<<1, 512, 0, stream>>>(em, eqcnt, out);
}